// Round 14
// baseline (134.965 us; speedup 1.0000x reference)
//
#include <hip/hip_runtime.h>
#include <hip/hip_fp16.h>

#define H 64
#define BSH 8            // 256 nodes per bucket
#define BNODES 256
#define NBMAX 256
#define TILE 2048
#define EPT 8            // edges per thread in k_part
#define BCAP 9216        // capacity per bucket (mean 8163, sd ~90)

typedef _Float16 half4 __attribute__((ext_vector_type(4)));
typedef float f32x4 __attribute__((ext_vector_type(4)));

// ---------- zero the bucket cursors ----------
__global__ void k_zero(int* __restrict__ p, int n) {
    int i = threadIdx.x + blockIdx.x * blockDim.x;
    if (i < n) p[i] = 0;
}

// ---------- exclusive scan of bucket counts ----------
__global__ __launch_bounds__(NBMAX) void k_bbase(const int* __restrict__ bcnt,
                                                 int* __restrict__ bbase, int nb) {
    __shared__ int s[NBMAX];
    int t = threadIdx.x;
    int v0 = (t < nb) ? bcnt[t] : 0;
    s[t] = v0;
    __syncthreads();
    #pragma unroll
    for (int d = 1; d < NBMAX; d <<= 1) {
        int v = (t >= d) ? s[t - d] : 0;
        __syncthreads();
        s[t] += v;
        __syncthreads();
    }
    if (t < nb) bbase[t] = s[t] - v0;
}

// ---------- pass A: partition edges into 256-node dst-buckets ----------
// entry = src (16b) | type<<16 (3b) | (dst&255)<<19 (8b)
__global__ __launch_bounds__(256) void k_part(const int* __restrict__ gsrc,
                                              const int* __restrict__ gdst,
                                              const int* __restrict__ type,
                                              int* __restrict__ bcur,
                                              int* __restrict__ barr,
                                              int E, int nb) {
    __shared__ int hist[NBMAX];
    __shared__ int scan[NBMAX];
    __shared__ int gpos[NBMAX];
    __shared__ int cursor[NBMAX];
    __shared__ int stage[TILE];
    __shared__ unsigned char bof[TILE];
    int t = threadIdx.x;
    int base = blockIdx.x * TILE;
    hist[t] = 0;
    __syncthreads();
    int myb[EPT]; int mypk[EPT];
    #pragma unroll
    for (int k = 0; k < EPT; ++k) {
        int j = base + k * 256 + t;             // coalesced
        if (j < E) {
            int d = gdst[j];
            int s = gsrc[j];
            int ty = type[s];                   // scattered 4B (L2-resident)
            int b = d >> BSH;
            myb[k] = b;
            mypk[k] = s | (ty << 16) | ((d & (BNODES - 1)) << 19);
            atomicAdd(&hist[b], 1);
        } else myb[k] = -1;
    }
    __syncthreads();
    int h0 = hist[t];
    scan[t] = h0;
    __syncthreads();
    #pragma unroll
    for (int d = 1; d < NBMAX; d <<= 1) {
        int v = (t >= d) ? scan[t - d] : 0;
        __syncthreads();
        scan[t] += v;
        __syncthreads();
    }
    int pfx_t = scan[t] - h0;                   // exclusive
    cursor[t] = pfx_t;
    if (t < nb) gpos[t] = h0 ? atomicAdd(&bcur[t], h0) : 0;
    __syncthreads();
    #pragma unroll
    for (int k = 0; k < EPT; ++k) if (myb[k] >= 0) {
        int p = atomicAdd(&cursor[myb[k]], 1);
        stage[p] = mypk[k];
        bof[p] = (unsigned char)myb[k];
    }
    __syncthreads();
    int total = scan[nb - 1];
    for (int i = t; i < total; i += 256) {       // coalesced segment write-out
        int b = bof[i];
        barr[(size_t)b * BCAP + gpos[b] + (i - (scan[b] - hist[b]))] = stage[i];
    }
}

// ---------- pass B: per-bucket counting sort + layer-1 (algebraic) fused ----------
__global__ __launch_bounds__(256) void k_bsort(const int* __restrict__ bcnt,
                                               const int* __restrict__ bbase,
                                               const int* __restrict__ barr,
                                               const int* __restrict__ type,
                                               const float* __restrict__ embed,
                                               const float* __restrict__ W1,
                                               const float* __restrict__ b1,
                                               int* __restrict__ csr,
                                               int* __restrict__ cnt,
                                               int* __restrict__ off,
                                               __half* __restrict__ x1h,
                                               int N, int nb) {
    __shared__ float W1s[H * H];        // 16KB
    __shared__ float es[8 * H];         // 2KB
    __shared__ float ews[8 * H];        // 2KB  EW = embed @ W1
    __shared__ float bs1[H];
    __shared__ int hist[BNODES];
    __shared__ int loff[BNODES];
    __shared__ int scan[BNODES];
    __shared__ int thist[BNODES * 8];   // 8KB per-node x type
    int b = blockIdx.x;
    int t = threadIdx.x;
    int n0 = b << BSH;
    int nn = min(BNODES, N - n0);
    int cE = bcnt[b];
    int cbase = bbase[b];
    const int* arr = barr + (size_t)b * BCAP;
    for (int i = t; i < H * H; i += 256) W1s[i] = W1[i];
    for (int i = t; i < 8 * H; i += 256) es[i] = embed[i];
    if (t < H) bs1[t] = b1[t];
    hist[t] = 0;
    for (int i = t; i < BNODES * 8; i += 256) thist[i] = 0;
    __syncthreads();
    // EW = e @ W1 (512 outputs, 2 per thread)
    {
        float a1 = 0.f, a2 = 0.f;
        int o1 = t, o2 = t + 256;
        int ty1 = o1 >> 6, n1 = o1 & 63, ty2 = o2 >> 6, n2 = o2 & 63;
        for (int k = 0; k < H; ++k) {
            a1 = fmaf(es[ty1 * H + k], W1s[k * H + n1], a1);
            a2 = fmaf(es[ty2 * H + k], W1s[k * H + n2], a2);
        }
        ews[o1] = a1; ews[o2] = a2;
    }
    // histogram over this bucket's edges (node + node-x-type)
    for (int i = t; i < cE; i += 256) {
        int e = arr[i];
        int loc = (e >> 19) & (BNODES - 1);
        atomicAdd(&hist[loc], 1);
        atomicAdd(&thist[loc * 8 + ((e >> 16) & 7)], 1);
    }
    __syncthreads();
    int h0 = hist[t];
    scan[t] = h0;
    __syncthreads();
    #pragma unroll
    for (int d = 1; d < BNODES; d <<= 1) {
        int v = (t >= d) ? scan[t - d] : 0;
        __syncthreads();
        scan[t] += v;
        __syncthreads();
    }
    loff[t] = scan[t] - h0;
    if (t < nn) {
        cnt[n0 + t] = h0;
        off[n0 + t] = cbase + loff[t];
    }
    __syncthreads();
    for (int i = t; i < cE; i += 256) {
        int e = arr[i];
        int p = atomicAdd(&loff[(e >> 19) & (BNODES - 1)], 1);
        csr[cbase + p] = e & 0x7FFFF;            // src | type<<16
    }
    __syncthreads();
    // layer-1 output: wave per node round-robin
    int lane = t & 63, w = t >> 6;
    for (int v = w; v < nn; v += 4) {
        int c = hist[v];
        float invc = (c > 0) ? 1.f / (float)c : 0.f;
        int tv = type[n0 + v];
        float z = bs1[lane] + ews[tv * H + lane];
        #pragma unroll
        for (int ty = 0; ty < 8; ++ty)
            z = fmaf((float)thist[v * 8 + ty] * invc, ews[ty * H + lane], z);
        x1h[(size_t)(n0 + v) * H + lane] = __float2half_rn(fmaxf(z, 0.f));
    }
}

__device__ __forceinline__ float2 h2f2(unsigned u) {
    __half2 h = *reinterpret_cast<__half2*>(&u);
    return __half22float2(h);
}

// ---------- layer-2 aggregation: 2 nodes per wave, interleaved gather chains ----------
__global__ __launch_bounds__(256) void k_l2agg(const __half* __restrict__ x1h,
                                               __half* __restrict__ h,
                                               const int* __restrict__ off,
                                               const int* __restrict__ cnt,
                                               const int* __restrict__ csr, int n) {
    int lane = threadIdx.x & 63;
    int oct = lane >> 3;         // which of 8 rows per j-step
    int sl = lane & 7;           // dim group: dims 8*sl..8*sl+7
    int wid = (blockIdx.x * blockDim.x + threadIdx.x) >> 6;
    int nw = (gridDim.x * blockDim.x) >> 6;
    const uint4* xh4 = (const uint4*)x1h;   // row = 8 x uint4 (64 halves)
    for (int v = wid; v < n; v += 2 * nw) {
        int v2 = v + nw;
        bool has2 = v2 < n;
        int lo1 = off[v], c1 = cnt[v];
        int lo2 = has2 ? off[v2] : 0;
        int c2 = has2 ? cnt[v2] : 0;
        float a1[8] = {0,0,0,0,0,0,0,0};
        float a2[8] = {0,0,0,0,0,0,0,0};
        int cmax = max(c1, c2);
        for (int i = 0; i < cmax; i += 32) {
            int idx1 = (i < c1) ? csr[lo1 + min(i + (lane & 31), c1 - 1)] : 0;
            int idx2 = (i < c2) ? csr[lo2 + min(i + (lane & 31), c2 - 1)] : 0;
            #pragma unroll
            for (int j = 0; j < 4; ++j) {
                int r = i + j * 8 + oct;
                int s1 = __shfl(idx1, j * 8 + oct, 64) & 0xffff;
                int s2 = __shfl(idx2, j * 8 + oct, 64) & 0xffff;
                uint4 u1 = xh4[(size_t)s1 * 8 + sl];
                uint4 u2 = xh4[(size_t)s2 * 8 + sl];
                float m1 = (r < c1) ? 1.f : 0.f;
                float m2 = (r < c2) ? 1.f : 0.f;
                float2 f0 = h2f2(u1.x), f1 = h2f2(u1.y), f2 = h2f2(u1.z), f3 = h2f2(u1.w);
                a1[0] = fmaf(m1, f0.x, a1[0]);
                a1[1] = fmaf(m1, f0.y, a1[1]);
                a1[2] = fmaf(m1, f1.x, a1[2]);
                a1[3] = fmaf(m1, f1.y, a1[3]);
                a1[4] = fmaf(m1, f2.x, a1[4]);
                a1[5] = fmaf(m1, f2.y, a1[5]);
                a1[6] = fmaf(m1, f3.x, a1[6]);
                a1[7] = fmaf(m1, f3.y, a1[7]);
                float2 g0 = h2f2(u2.x), g1 = h2f2(u2.y), g2 = h2f2(u2.z), g3 = h2f2(u2.w);
                a2[0] = fmaf(m2, g0.x, a2[0]);
                a2[1] = fmaf(m2, g0.y, a2[1]);
                a2[2] = fmaf(m2, g1.x, a2[2]);
                a2[3] = fmaf(m2, g1.y, a2[3]);
                a2[4] = fmaf(m2, g2.x, a2[4]);
                a2[5] = fmaf(m2, g2.y, a2[5]);
                a2[6] = fmaf(m2, g3.x, a2[6]);
                a2[7] = fmaf(m2, g3.y, a2[7]);
            }
        }
        #pragma unroll
        for (int d = 8; d < 64; d <<= 1) {
            #pragma unroll
            for (int k = 0; k < 8; ++k) {
                a1[k] += __shfl_xor(a1[k], d, 64);
                a2[k] += __shfl_xor(a2[k], d, 64);
            }
        }
        uint4 us1 = xh4[(size_t)v * 8 + sl];
        float inv1 = (c1 > 0) ? 1.f / (float)c1 : 0.f;
        float2 s0 = h2f2(us1.x), s1f = h2f2(us1.y), s2f = h2f2(us1.z), s3f = h2f2(us1.w);
        if (oct == 0) {
            __half2 p0 = __floats2half2_rn(s0.x + a1[0] * inv1, s0.y + a1[1] * inv1);
            __half2 p1 = __floats2half2_rn(s1f.x + a1[2] * inv1, s1f.y + a1[3] * inv1);
            __half2 p2 = __floats2half2_rn(s2f.x + a1[4] * inv1, s2f.y + a1[5] * inv1);
            __half2 p3 = __floats2half2_rn(s3f.x + a1[6] * inv1, s3f.y + a1[7] * inv1);
            uint4 o;
            o.x = *(unsigned*)&p0; o.y = *(unsigned*)&p1;
            o.z = *(unsigned*)&p2; o.w = *(unsigned*)&p3;
            ((uint4*)h)[(size_t)v * 8 + sl] = o;
        }
        if (has2) {
            uint4 us2 = xh4[(size_t)v2 * 8 + sl];
            float inv2 = (c2 > 0) ? 1.f / (float)c2 : 0.f;
            float2 t0 = h2f2(us2.x), t1 = h2f2(us2.y), t2 = h2f2(us2.z), t3 = h2f2(us2.w);
            if (oct == 0) {
                __half2 p0 = __floats2half2_rn(t0.x + a2[0] * inv2, t0.y + a2[1] * inv2);
                __half2 p1 = __floats2half2_rn(t1.x + a2[2] * inv2, t1.y + a2[3] * inv2);
                __half2 p2 = __floats2half2_rn(t2.x + a2[4] * inv2, t2.y + a2[5] * inv2);
                __half2 p3 = __floats2half2_rn(t3.x + a2[6] * inv2, t3.y + a2[7] * inv2);
                uint4 o;
                o.x = *(unsigned*)&p0; o.y = *(unsigned*)&p1;
                o.z = *(unsigned*)&p2; o.w = *(unsigned*)&p3;
                ((uint4*)h)[(size_t)v2 * 8 + sl] = o;
            }
        }
    }
}

// ---------- MFMA MLP: x2 = relu(h@W2+b2); A = x2@We1_top+be1; B = x2@We1_bot ----------
__global__ __launch_bounds__(256) void k_mlp(const __half* __restrict__ h,
                                             const float* __restrict__ W2,
                                             const float* __restrict__ b2,
                                             const float* __restrict__ We1,
                                             const float* __restrict__ be1,
                                             __half* __restrict__ A,
                                             __half* __restrict__ B, int n) {
    int lane = threadIdx.x & 63;
    int r = lane & 15;          // tile row (weights) / node column (data)
    int g = lane >> 4;          // k-group
    half4 w2f[4][4];
    #pragma unroll
    for (int tr = 0; tr < 4; ++tr)
        #pragma unroll
        for (int tk = 0; tk < 4; ++tk)
            #pragma unroll
            for (int i = 0; i < 4; ++i)
                w2f[tr][tk][i] = (_Float16)W2[(16 * tk + 4 * g + i) * H + 16 * tr + r];
    half4 we1t[4][4], we1b[4][4];
    #pragma unroll
    for (int tr = 0; tr < 4; ++tr)
        #pragma unroll
        for (int tk = 0; tk < 4; ++tk)
            #pragma unroll
            for (int i = 0; i < 4; ++i) {
                we1t[tr][tk][i] = (_Float16)We1[(16 * tk + 4 * g + i) * H + 16 * tr + r];
                we1b[tr][tk][i] = (_Float16)We1[(64 + 16 * tk + 4 * g + i) * H + 16 * tr + r];
            }
    f32x4 b2f[4], be1f[4];
    #pragma unroll
    for (int tr = 0; tr < 4; ++tr)
        #pragma unroll
        for (int i = 0; i < 4; ++i) {
            b2f[tr][i] = b2[16 * tr + 4 * g + i];
            be1f[tr][i] = be1[16 * tr + 4 * g + i];
        }
    int wid = (blockIdx.x * blockDim.x + threadIdx.x) >> 6;
    int nw = (gridDim.x * blockDim.x) >> 6;
    const uint2* h2p = (const uint2*)h;     // h row = 16 x uint2
    for (int t0 = wid * 16; t0 < n; t0 += nw * 16) {
        int node = t0 + r;
        bool nvalid = node < n;
        int nclamp = nvalid ? node : (n - 1);
        half4 hb[4];
        #pragma unroll
        for (int tk = 0; tk < 4; ++tk) {
            uint2 u = h2p[(size_t)nclamp * 16 + 4 * tk + g];
            hb[tk] = *(half4*)&u;
        }
        f32x4 d1[4];
        #pragma unroll
        for (int tr = 0; tr < 4; ++tr) d1[tr] = b2f[tr];
        #pragma unroll
        for (int tr = 0; tr < 4; ++tr)
            #pragma unroll
            for (int tk = 0; tk < 4; ++tk)
                d1[tr] = __builtin_amdgcn_mfma_f32_16x16x16f16(w2f[tr][tk], hb[tk], d1[tr], 0, 0, 0);
        half4 xb[4];
        #pragma unroll
        for (int tk2 = 0; tk2 < 4; ++tk2)
            #pragma unroll
            for (int i = 0; i < 4; ++i)
                xb[tk2][i] = (_Float16)fmaxf(d1[tk2][i], 0.f);
        f32x4 dA[4], dB[4];
        #pragma unroll
        for (int tr = 0; tr < 4; ++tr) { dA[tr] = be1f[tr]; dB[tr] = 0.f; }
        #pragma unroll
        for (int tr = 0; tr < 4; ++tr)
            #pragma unroll
            for (int tk = 0; tk < 4; ++tk) {
                dA[tr] = __builtin_amdgcn_mfma_f32_16x16x16f16(we1t[tr][tk], xb[tk], dA[tr], 0, 0, 0);
                dB[tr] = __builtin_amdgcn_mfma_f32_16x16x16f16(we1b[tr][tk], xb[tk], dB[tr], 0, 0, 0);
            }
        if (nvalid) {
            #pragma unroll
            for (int tr = 0; tr < 4; ++tr) {
                __half2 a0 = __floats2half2_rn(dA[tr][0], dA[tr][1]);
                __half2 a1 = __floats2half2_rn(dA[tr][2], dA[tr][3]);
                __half2 c0 = __floats2half2_rn(dB[tr][0], dB[tr][1]);
                __half2 c1 = __floats2half2_rn(dB[tr][2], dB[tr][3]);
                uint2 pa, pb;
                pa.x = *(unsigned*)&a0; pa.y = *(unsigned*)&a1;
                pb.x = *(unsigned*)&c0; pb.y = *(unsigned*)&c1;
                ((uint2*)A)[(size_t)node * 16 + 4 * tr + g] = pa;
                ((uint2*)B)[(size_t)node * 16 + 4 * tr + g] = pb;
            }
        }
    }
}

// ---------- query edge scoring: one-shot, 8 edges/wave, 8 lanes/edge ----------
__global__ __launch_bounds__(256) void k_edge(const __half* __restrict__ A,
                                              const __half* __restrict__ B,
                                              const int* __restrict__ qs,
                                              const int* __restrict__ qd,
                                              const float* __restrict__ We2,
                                              const float* __restrict__ be2,
                                              float* __restrict__ out, int q) {
    const uint4* A4 = (const uint4*)A;
    const uint4* B4 = (const uint4*)B;
    int lane = threadIdx.x & 63;
    int sub  = lane >> 3;
    int sl   = lane & 7;
    int wid = (blockIdx.x * blockDim.x + threadIdx.x) >> 6;
    const float4* W24 = (const float4*)We2;
    float4 wlo = W24[sl * 2];
    float4 whi = W24[sl * 2 + 1];
    float b2 = be2[0];
    int e = wid * 8 + sub;
    if (e < q) {
        int u = qs[e], v = qd[e];
        uint4 ra = A4[(size_t)u * 8 + sl];
        uint4 rb = B4[(size_t)v * 8 + sl];
        float2 a0 = h2f2(ra.x), a1 = h2f2(ra.y), a2 = h2f2(ra.z), a3 = h2f2(ra.w);
        float2 b0 = h2f2(rb.x), b1 = h2f2(rb.y), b2v = h2f2(rb.z), b3 = h2f2(rb.w);
        float p = fmaxf(a0.x + b0.x, 0.f) * wlo.x
                + fmaxf(a0.y + b0.y, 0.f) * wlo.y
                + fmaxf(a1.x + b1.x, 0.f) * wlo.z
                + fmaxf(a1.y + b1.y, 0.f) * wlo.w
                + fmaxf(a2.x + b2v.x, 0.f) * whi.x
                + fmaxf(a2.y + b2v.y, 0.f) * whi.y
                + fmaxf(a3.x + b3.x, 0.f) * whi.z
                + fmaxf(a3.y + b3.y, 0.f) * whi.w;
        p += __shfl_xor(p, 1, 64);
        p += __shfl_xor(p, 2, 64);
        p += __shfl_xor(p, 4, 64);
        if (sl == 0) out[e] = p + b2;
    }
}

extern "C" void kernel_launch(void* const* d_in, const int* in_sizes, int n_in,
                              void* d_out, int out_size, void* d_ws, size_t ws_size,
                              hipStream_t stream) {
    const int* node_type = (const int*)d_in[0];
    const int* gsrc      = (const int*)d_in[1];
    const int* gdst      = (const int*)d_in[2];
    const int* qsrc      = (const int*)d_in[3];
    const int* qdst      = (const int*)d_in[4];
    const float* embed   = (const float*)d_in[5];
    const float* W1      = (const float*)d_in[6];
    const float* b1      = (const float*)d_in[7];
    const float* W2      = (const float*)d_in[8];
    const float* b2      = (const float*)d_in[9];
    const float* We1     = (const float*)d_in[10];
    const float* be1     = (const float*)d_in[11];
    const float* We2     = (const float*)d_in[12];
    const float* be2     = (const float*)d_in[13];
    float* out = (float*)d_out;

    const int N = in_sizes[0];
    const int E = in_sizes[1];
    const int Q = in_sizes[3];
    const int nb = (N + BNODES - 1) >> BSH;    // 196 buckets

    // workspace layout (256B aligned)
    char* ws = (char*)d_ws;
    size_t o = 0;
    auto alloc = [&](size_t bytes) { void* p = ws + o; o = (o + bytes + 255) & ~(size_t)255; return p; };
    __half* x1h = (__half*)alloc((size_t)N * H * sizeof(__half));
    __half* hbuf = (__half*)alloc((size_t)N * H * sizeof(__half));
    __half* Ah  = (__half*)alloc((size_t)N * H * sizeof(__half));
    __half* Bh  = (__half*)alloc((size_t)N * H * sizeof(__half));
    int* cnt  = (int*)alloc((size_t)N * sizeof(int));
    int* off  = (int*)alloc((size_t)N * sizeof(int));
    int* csr  = (int*)alloc((size_t)E * sizeof(int));
    int* barr = (int*)alloc((size_t)nb * BCAP * sizeof(int));
    int* bcur = (int*)alloc((size_t)NBMAX * sizeof(int));
    int* bbase= (int*)alloc((size_t)NBMAX * sizeof(int));
    (void)ws_size;

    // bucketed CSR build + fused layer 1
    k_zero<<<1, NBMAX, 0, stream>>>(bcur, NBMAX);
    k_part<<<(E + TILE - 1) / TILE, 256, 0, stream>>>(gsrc, gdst, node_type, bcur, barr, E, nb);
    k_bbase<<<1, NBMAX, 0, stream>>>(bcur, bbase, nb);
    k_bsort<<<nb, 256, 0, stream>>>(bcur, bbase, barr, node_type, embed, W1, b1,
                                    csr, cnt, off, x1h, N, nb);

    // layer-2 aggregation (gather only, 2 nodes/wave)
    k_l2agg<<<4096, 256, 0, stream>>>(x1h, hbuf, off, cnt, csr, N);

    // MFMA MLP: h -> x2 -> A,B
    k_mlp<<<196, 256, 0, stream>>>(hbuf, W2, b2, We1, be1, Ah, Bh, N);

    // per-edge scoring
    int eblocks = (Q + 31) / 32;   // 4 waves/block x 8 edges/wave
    k_edge<<<eblocks, 256, 0, stream>>>(Ah, Bh, qsrc, qdst, We2, be2, out, Q);
}

// Round 15
// 126.375 us; speedup vs baseline: 1.0680x; 1.0680x over previous
//
#include <hip/hip_runtime.h>
#include <hip/hip_fp16.h>

#define H 64
#define BSH 8            // 256 nodes per bucket
#define BNODES 256
#define NBMAX 256
#define TILE 2048
#define EPT 8            // edges per thread in k_part
#define BCAP 9216        // capacity per bucket (mean 8163, sd ~90)

typedef _Float16 half4 __attribute__((ext_vector_type(4)));
typedef float f32x4 __attribute__((ext_vector_type(4)));

// ---------- zero the bucket cursors ----------
__global__ void k_zero(int* __restrict__ p, int n) {
    int i = threadIdx.x + blockIdx.x * blockDim.x;
    if (i < n) p[i] = 0;
}

// ---------- exclusive scan of bucket counts (replaces per-block serial loops) ----------
__global__ __launch_bounds__(NBMAX) void k_bbase(const int* __restrict__ bcnt,
                                                 int* __restrict__ bbase, int nb) {
    __shared__ int s[NBMAX];
    int t = threadIdx.x;
    int v0 = (t < nb) ? bcnt[t] : 0;
    s[t] = v0;
    __syncthreads();
    #pragma unroll
    for (int d = 1; d < NBMAX; d <<= 1) {
        int v = (t >= d) ? s[t - d] : 0;
        __syncthreads();
        s[t] += v;
        __syncthreads();
    }
    if (t < nb) bbase[t] = s[t] - v0;
}

// ---------- pass A: partition edges into 256-node dst-buckets ----------
// entry = src (16b) | type<<16 (3b) | (dst&255)<<19 (8b)
__global__ __launch_bounds__(256) void k_part(const int* __restrict__ gsrc,
                                              const int* __restrict__ gdst,
                                              const int* __restrict__ type,
                                              int* __restrict__ bcur,
                                              int* __restrict__ barr,
                                              int E, int nb) {
    __shared__ int hist[NBMAX];
    __shared__ int scan[NBMAX];
    __shared__ int gpos[NBMAX];
    __shared__ int cursor[NBMAX];
    __shared__ int stage[TILE];
    __shared__ unsigned char bof[TILE];
    int t = threadIdx.x;
    int base = blockIdx.x * TILE;
    hist[t] = 0;
    __syncthreads();
    int myb[EPT]; int mypk[EPT];
    #pragma unroll
    for (int k = 0; k < EPT; ++k) {
        int j = base + k * 256 + t;             // coalesced
        if (j < E) {
            int d = gdst[j];
            int s = gsrc[j];
            int ty = type[s];                   // scattered 4B (L2-resident)
            int b = d >> BSH;
            myb[k] = b;
            mypk[k] = s | (ty << 16) | ((d & (BNODES - 1)) << 19);
            atomicAdd(&hist[b], 1);
        } else myb[k] = -1;
    }
    __syncthreads();
    // parallel exclusive prefix (Hillis-Steele over NBMAX)
    int h0 = hist[t];
    scan[t] = h0;
    __syncthreads();
    #pragma unroll
    for (int d = 1; d < NBMAX; d <<= 1) {
        int v = (t >= d) ? scan[t - d] : 0;
        __syncthreads();
        scan[t] += v;
        __syncthreads();
    }
    int pfx_t = scan[t] - h0;                   // exclusive
    cursor[t] = pfx_t;
    if (t < nb) gpos[t] = h0 ? atomicAdd(&bcur[t], h0) : 0;
    __syncthreads();
    #pragma unroll
    for (int k = 0; k < EPT; ++k) if (myb[k] >= 0) {
        int p = atomicAdd(&cursor[myb[k]], 1);
        stage[p] = mypk[k];
        bof[p] = (unsigned char)myb[k];
    }
    __syncthreads();
    int total = scan[nb - 1];
    for (int i = t; i < total; i += 256) {       // coalesced segment write-out
        int b = bof[i];
        barr[(size_t)b * BCAP + gpos[b] + (i - (scan[b] - hist[b]))] = stage[i];
    }
}

// ---------- pass B: per-bucket counting sort + layer-1 (algebraic) fused ----------
__global__ __launch_bounds__(256) void k_bsort(const int* __restrict__ bcnt,
                                               const int* __restrict__ bbase,
                                               const int* __restrict__ barr,
                                               const int* __restrict__ type,
                                               const float* __restrict__ embed,
                                               const float* __restrict__ W1,
                                               const float* __restrict__ b1,
                                               int* __restrict__ csr,
                                               int* __restrict__ cnt,
                                               int* __restrict__ off,
                                               __half* __restrict__ x1h,
                                               int N, int nb) {
    __shared__ float W1s[H * H];        // 16KB
    __shared__ float es[8 * H];         // 2KB
    __shared__ float ews[8 * H];        // 2KB  EW = embed @ W1
    __shared__ float bs1[H];
    __shared__ int hist[BNODES];
    __shared__ int loff[BNODES];
    __shared__ int scan[BNODES];
    __shared__ int thist[BNODES * 8];   // 8KB per-node x type
    int b = blockIdx.x;
    int t = threadIdx.x;
    int n0 = b << BSH;
    int nn = min(BNODES, N - n0);
    int cE = bcnt[b];
    int cbase = bbase[b];
    const int* arr = barr + (size_t)b * BCAP;
    for (int i = t; i < H * H; i += 256) W1s[i] = W1[i];
    for (int i = t; i < 8 * H; i += 256) es[i] = embed[i];
    if (t < H) bs1[t] = b1[t];
    hist[t] = 0;
    for (int i = t; i < BNODES * 8; i += 256) thist[i] = 0;
    __syncthreads();
    // EW = e @ W1 (512 outputs, 2 per thread)
    {
        float a1 = 0.f, a2 = 0.f;
        int o1 = t, o2 = t + 256;
        int ty1 = o1 >> 6, n1 = o1 & 63, ty2 = o2 >> 6, n2 = o2 & 63;
        for (int k = 0; k < H; ++k) {
            a1 = fmaf(es[ty1 * H + k], W1s[k * H + n1], a1);
            a2 = fmaf(es[ty2 * H + k], W1s[k * H + n2], a2);
        }
        ews[o1] = a1; ews[o2] = a2;
    }
    // histogram over this bucket's edges (node + node-x-type)
    for (int i = t; i < cE; i += 256) {
        int e = arr[i];
        int loc = (e >> 19) & (BNODES - 1);
        atomicAdd(&hist[loc], 1);
        atomicAdd(&thist[loc * 8 + ((e >> 16) & 7)], 1);
    }
    __syncthreads();
    // parallel exclusive prefix over 256 node counts
    int h0 = hist[t];
    scan[t] = h0;
    __syncthreads();
    #pragma unroll
    for (int d = 1; d < BNODES; d <<= 1) {
        int v = (t >= d) ? scan[t - d] : 0;
        __syncthreads();
        scan[t] += v;
        __syncthreads();
    }
    loff[t] = scan[t] - h0;
    if (t < nn) {
        cnt[n0 + t] = h0;
        off[n0 + t] = cbase + loff[t];
    }
    __syncthreads();
    for (int i = t; i < cE; i += 256) {
        int e = arr[i];
        int p = atomicAdd(&loff[(e >> 19) & (BNODES - 1)], 1);
        csr[cbase + p] = e & 0x7FFFF;            // src | type<<16
    }
    __syncthreads();
    // layer-1 output: wave per node round-robin
    int lane = t & 63, w = t >> 6;
    for (int v = w; v < nn; v += 4) {
        int c = hist[v];
        float invc = (c > 0) ? 1.f / (float)c : 0.f;
        int tv = type[n0 + v];
        float z = bs1[lane] + ews[tv * H + lane];
        #pragma unroll
        for (int ty = 0; ty < 8; ++ty)
            z = fmaf((float)thist[v * 8 + ty] * invc, ews[ty * H + lane], z);
        x1h[(size_t)(n0 + v) * H + lane] = __float2half_rn(fmaxf(z, 0.f));
    }
}

__device__ __forceinline__ float2 h2f2(unsigned u) {
    __half2 h = *reinterpret_cast<__half2*>(&u);
    return __half22float2(h);
}

// ---------- layer-2 aggregation (chunk-32, masked; best-known form) ----------
__global__ __launch_bounds__(256) void k_l2agg(const __half* __restrict__ x1h,
                                               __half* __restrict__ h,
                                               const int* __restrict__ off,
                                               const int* __restrict__ cnt,
                                               const int* __restrict__ csr, int n) {
    int lane = threadIdx.x & 63;
    int oct = lane >> 3;         // which of 8 rows per j-step
    int sl = lane & 7;           // dim group: dims 8*sl..8*sl+7
    int wid = (blockIdx.x * blockDim.x + threadIdx.x) >> 6;
    int nw = (gridDim.x * blockDim.x) >> 6;
    const uint4* xh4 = (const uint4*)x1h;   // row = 8 x uint4 (64 halves)
    for (int v = wid; v < n; v += nw) {
        int lo = off[v];
        int c = cnt[v];
        float acc[8] = {0.f, 0.f, 0.f, 0.f, 0.f, 0.f, 0.f, 0.f};
        for (int i = 0; i < c; i += 32) {
            int idx = csr[lo + min(i + (lane & 31), c - 1)];   // coalesced
            #pragma unroll
            for (int j = 0; j < 4; ++j) {
                int r = i + j * 8 + oct;
                int s = __shfl(idx, j * 8 + oct, 64) & 0xffff;
                uint4 u = xh4[(size_t)s * 8 + sl];
                float m = (r < c) ? 1.f : 0.f;
                float2 f0 = h2f2(u.x), f1 = h2f2(u.y), f2 = h2f2(u.z), f3 = h2f2(u.w);
                acc[0] = fmaf(m, f0.x, acc[0]);
                acc[1] = fmaf(m, f0.y, acc[1]);
                acc[2] = fmaf(m, f1.x, acc[2]);
                acc[3] = fmaf(m, f1.y, acc[3]);
                acc[4] = fmaf(m, f2.x, acc[4]);
                acc[5] = fmaf(m, f2.y, acc[5]);
                acc[6] = fmaf(m, f3.x, acc[6]);
                acc[7] = fmaf(m, f3.y, acc[7]);
            }
        }
        #pragma unroll
        for (int d = 8; d < 64; d <<= 1) {
            #pragma unroll
            for (int k = 0; k < 8; ++k) acc[k] += __shfl_xor(acc[k], d, 64);
        }
        uint4 us = xh4[(size_t)v * 8 + sl];   // self row
        float inv = (c > 0) ? 1.f / (float)c : 0.f;
        float2 s0 = h2f2(us.x), s1 = h2f2(us.y), s2 = h2f2(us.z), s3 = h2f2(us.w);
        if (oct == 0) {                        // 8 lanes cover the 128B row
            __half2 p0 = __floats2half2_rn(s0.x + acc[0] * inv, s0.y + acc[1] * inv);
            __half2 p1 = __floats2half2_rn(s1.x + acc[2] * inv, s1.y + acc[3] * inv);
            __half2 p2 = __floats2half2_rn(s2.x + acc[4] * inv, s2.y + acc[5] * inv);
            __half2 p3 = __floats2half2_rn(s3.x + acc[6] * inv, s3.y + acc[7] * inv);
            uint4 o;
            o.x = *(unsigned*)&p0; o.y = *(unsigned*)&p1;
            o.z = *(unsigned*)&p2; o.w = *(unsigned*)&p3;
            ((uint4*)h)[(size_t)v * 8 + sl] = o;
        }
    }
}

// ---------- MFMA MLP: x2 = relu(h@W2+b2); A = x2@We1_top+be1; B = x2@We1_bot ----------
__global__ __launch_bounds__(256) void k_mlp(const __half* __restrict__ h,
                                             const float* __restrict__ W2,
                                             const float* __restrict__ b2,
                                             const float* __restrict__ We1,
                                             const float* __restrict__ be1,
                                             __half* __restrict__ A,
                                             __half* __restrict__ B, int n) {
    int lane = threadIdx.x & 63;
    int r = lane & 15;          // tile row (weights) / node column (data)
    int g = lane >> 4;          // k-group
    half4 w2f[4][4];
    #pragma unroll
    for (int tr = 0; tr < 4; ++tr)
        #pragma unroll
        for (int tk = 0; tk < 4; ++tk)
            #pragma unroll
            for (int i = 0; i < 4; ++i)
                w2f[tr][tk][i] = (_Float16)W2[(16 * tk + 4 * g + i) * H + 16 * tr + r];
    half4 we1t[4][4], we1b[4][4];
    #pragma unroll
    for (int tr = 0; tr < 4; ++tr)
        #pragma unroll
        for (int tk = 0; tk < 4; ++tk)
            #pragma unroll
            for (int i = 0; i < 4; ++i) {
                we1t[tr][tk][i] = (_Float16)We1[(16 * tk + 4 * g + i) * H + 16 * tr + r];
                we1b[tr][tk][i] = (_Float16)We1[(64 + 16 * tk + 4 * g + i) * H + 16 * tr + r];
            }
    f32x4 b2f[4], be1f[4];
    #pragma unroll
    for (int tr = 0; tr < 4; ++tr)
        #pragma unroll
        for (int i = 0; i < 4; ++i) {
            b2f[tr][i] = b2[16 * tr + 4 * g + i];
            be1f[tr][i] = be1[16 * tr + 4 * g + i];
        }
    int wid = (blockIdx.x * blockDim.x + threadIdx.x) >> 6;
    int nw = (gridDim.x * blockDim.x) >> 6;
    const uint2* h2p = (const uint2*)h;     // h row = 16 x uint2
    for (int t0 = wid * 16; t0 < n; t0 += nw * 16) {
        int node = t0 + r;
        bool nvalid = node < n;
        int nclamp = nvalid ? node : (n - 1);
        half4 hb[4];
        #pragma unroll
        for (int tk = 0; tk < 4; ++tk) {
            uint2 u = h2p[(size_t)nclamp * 16 + 4 * tk + g];
            hb[tk] = *(half4*)&u;
        }
        f32x4 d1[4];
        #pragma unroll
        for (int tr = 0; tr < 4; ++tr) d1[tr] = b2f[tr];
        #pragma unroll
        for (int tr = 0; tr < 4; ++tr)
            #pragma unroll
            for (int tk = 0; tk < 4; ++tk)
                d1[tr] = __builtin_amdgcn_mfma_f32_16x16x16f16(w2f[tr][tk], hb[tk], d1[tr], 0, 0, 0);
        half4 xb[4];
        #pragma unroll
        for (int tk2 = 0; tk2 < 4; ++tk2)
            #pragma unroll
            for (int i = 0; i < 4; ++i)
                xb[tk2][i] = (_Float16)fmaxf(d1[tk2][i], 0.f);
        f32x4 dA[4], dB[4];
        #pragma unroll
        for (int tr = 0; tr < 4; ++tr) { dA[tr] = be1f[tr]; dB[tr] = 0.f; }
        #pragma unroll
        for (int tr = 0; tr < 4; ++tr)
            #pragma unroll
            for (int tk = 0; tk < 4; ++tk) {
                dA[tr] = __builtin_amdgcn_mfma_f32_16x16x16f16(we1t[tr][tk], xb[tk], dA[tr], 0, 0, 0);
                dB[tr] = __builtin_amdgcn_mfma_f32_16x16x16f16(we1b[tr][tk], xb[tk], dB[tr], 0, 0, 0);
            }
        if (nvalid) {
            #pragma unroll
            for (int tr = 0; tr < 4; ++tr) {
                __half2 a0 = __floats2half2_rn(dA[tr][0], dA[tr][1]);
                __half2 a1 = __floats2half2_rn(dA[tr][2], dA[tr][3]);
                __half2 c0 = __floats2half2_rn(dB[tr][0], dB[tr][1]);
                __half2 c1 = __floats2half2_rn(dB[tr][2], dB[tr][3]);
                uint2 pa, pb;
                pa.x = *(unsigned*)&a0; pa.y = *(unsigned*)&a1;
                pb.x = *(unsigned*)&c0; pb.y = *(unsigned*)&c1;
                ((uint2*)A)[(size_t)node * 16 + 4 * tr + g] = pa;
                ((uint2*)B)[(size_t)node * 16 + 4 * tr + g] = pb;
            }
        }
    }
}

// ---------- query edge scoring: one-shot, 8 edges/wave, 8 lanes/edge ----------
__global__ __launch_bounds__(256) void k_edge(const __half* __restrict__ A,
                                              const __half* __restrict__ B,
                                              const int* __restrict__ qs,
                                              const int* __restrict__ qd,
                                              const float* __restrict__ We2,
                                              const float* __restrict__ be2,
                                              float* __restrict__ out, int q) {
    const uint4* A4 = (const uint4*)A;
    const uint4* B4 = (const uint4*)B;
    int lane = threadIdx.x & 63;
    int sub  = lane >> 3;
    int sl   = lane & 7;
    int wid = (blockIdx.x * blockDim.x + threadIdx.x) >> 6;
    const float4* W24 = (const float4*)We2;
    float4 wlo = W24[sl * 2];
    float4 whi = W24[sl * 2 + 1];
    float b2 = be2[0];
    int e = wid * 8 + sub;
    if (e < q) {
        int u = qs[e], v = qd[e];
        uint4 ra = A4[(size_t)u * 8 + sl];
        uint4 rb = B4[(size_t)v * 8 + sl];
        float2 a0 = h2f2(ra.x), a1 = h2f2(ra.y), a2 = h2f2(ra.z), a3 = h2f2(ra.w);
        float2 b0 = h2f2(rb.x), b1 = h2f2(rb.y), b2v = h2f2(rb.z), b3 = h2f2(rb.w);
        float p = fmaxf(a0.x + b0.x, 0.f) * wlo.x
                + fmaxf(a0.y + b0.y, 0.f) * wlo.y
                + fmaxf(a1.x + b1.x, 0.f) * wlo.z
                + fmaxf(a1.y + b1.y, 0.f) * wlo.w
                + fmaxf(a2.x + b2v.x, 0.f) * whi.x
                + fmaxf(a2.y + b2v.y, 0.f) * whi.y
                + fmaxf(a3.x + b3.x, 0.f) * whi.z
                + fmaxf(a3.y + b3.y, 0.f) * whi.w;
        p += __shfl_xor(p, 1, 64);
        p += __shfl_xor(p, 2, 64);
        p += __shfl_xor(p, 4, 64);
        if (sl == 0) out[e] = p + b2;
    }
}

extern "C" void kernel_launch(void* const* d_in, const int* in_sizes, int n_in,
                              void* d_out, int out_size, void* d_ws, size_t ws_size,
                              hipStream_t stream) {
    const int* node_type = (const int*)d_in[0];
    const int* gsrc      = (const int*)d_in[1];
    const int* gdst      = (const int*)d_in[2];
    const int* qsrc      = (const int*)d_in[3];
    const int* qdst      = (const int*)d_in[4];
    const float* embed   = (const float*)d_in[5];
    const float* W1      = (const float*)d_in[6];
    const float* b1      = (const float*)d_in[7];
    const float* W2      = (const float*)d_in[8];
    const float* b2      = (const float*)d_in[9];
    const float* We1     = (const float*)d_in[10];
    const float* be1     = (const float*)d_in[11];
    const float* We2     = (const float*)d_in[12];
    const float* be2     = (const float*)d_in[13];
    float* out = (float*)d_out;

    const int N = in_sizes[0];
    const int E = in_sizes[1];
    const int Q = in_sizes[3];
    const int nb = (N + BNODES - 1) >> BSH;    // 196 buckets

    // workspace layout (256B aligned)
    char* ws = (char*)d_ws;
    size_t o = 0;
    auto alloc = [&](size_t bytes) { void* p = ws + o; o = (o + bytes + 255) & ~(size_t)255; return p; };
    __half* x1h = (__half*)alloc((size_t)N * H * sizeof(__half));
    __half* hbuf = (__half*)alloc((size_t)N * H * sizeof(__half));
    __half* Ah  = (__half*)alloc((size_t)N * H * sizeof(__half));
    __half* Bh  = (__half*)alloc((size_t)N * H * sizeof(__half));
    int* cnt  = (int*)alloc((size_t)N * sizeof(int));
    int* off  = (int*)alloc((size_t)N * sizeof(int));
    int* csr  = (int*)alloc((size_t)E * sizeof(int));
    int* barr = (int*)alloc((size_t)nb * BCAP * sizeof(int));
    int* bcur = (int*)alloc((size_t)NBMAX * sizeof(int));
    int* bbase= (int*)alloc((size_t)NBMAX * sizeof(int));
    (void)ws_size;

    // bucketed CSR build + fused layer 1
    k_zero<<<1, NBMAX, 0, stream>>>(bcur, NBMAX);
    k_part<<<(E + TILE - 1) / TILE, 256, 0, stream>>>(gsrc, gdst, node_type, bcur, barr, E, nb);
    k_bbase<<<1, NBMAX, 0, stream>>>(bcur, bbase, nb);
    k_bsort<<<nb, 256, 0, stream>>>(bcur, bbase, barr, node_type, embed, W1, b1,
                                    csr, cnt, off, x1h, N, nb);

    // layer-2 aggregation (gather only)
    k_l2agg<<<4096, 256, 0, stream>>>(x1h, hbuf, off, cnt, csr, N);

    // MFMA MLP: h -> x2 -> A,B
    k_mlp<<<196, 256, 0, stream>>>(hbuf, W2, b2, We1, be1, Ah, Bh, N);

    // per-edge scoring
    int eblocks = (Q + 31) / 32;   // 4 waves/block x 8 edges/wave
    k_edge<<<eblocks, 256, 0, stream>>>(Ah, Bh, qsrc, qdst, We2, be2, out, Q);
}